// Round 16
// baseline (92.541 us; speedup 1.0000x reference)
//
#include <hip/hip_runtime.h>
#include <hip/hip_bf16.h>

#define BATCH 4096
#define NTOT  8192
#define DIM   512
#define NBLK  2080

typedef __attribute__((ext_vector_type(4))) float floatx4;
typedef __attribute__((ext_vector_type(8))) int   intx8;

#define ASYNC16(gp, lp)                                                        \
  __builtin_amdgcn_global_load_lds(                                            \
      (__attribute__((address_space(1))) void*)(gp),                           \
      (__attribute__((address_space(3))) void*)(lp), 16, 0, 0)

// e2m1 (OCP MXFP4) RNE quantizer for scaled value v; returns 4-bit code.
// Grid {0, 0.5, 1, 1.5, 2, 3, 4, 6}; code = index, sign in bit 3.
__device__ __forceinline__ unsigned q4(float v) {
  const float m = fabsf(v);
  int c;
  if      (m < 0.25f) c = 0;
  else if (m < 0.75f) c = 1;
  else if (m < 1.25f) c = 2;
  else if (m < 1.75f) c = 3;
  else if (m < 2.50f) c = 4;
  else if (m < 3.50f) c = 5;
  else if (m < 5.00f) c = 6;
  else                c = 7;
  return (unsigned)(c | (v < 0.0f ? 8 : 0));
}

// ---------------------------------------------------------------- normalize
// One wave per row: read 512 fp32, rsqrt(sum sq), write 512 fp4 e2m1 scaled
// by 64 (epilogue divides by 4096). Blocks 0..31 zero S; block 32 zeroes out.
__global__ __launch_bounds__(256) void nrm_kernel(const float* __restrict__ zi,
                                                  const float* __restrict__ zj,
                                                  unsigned char* __restrict__ zn,
                                                  float* __restrict__ S,
                                                  float* __restrict__ out) {
  if (blockIdx.x < 32) S[blockIdx.x * 256 + threadIdx.x] = 0.0f;
  if (blockIdx.x == 32 && threadIdx.x == 0) out[0] = 0.0f;
  const int row = blockIdx.x * 4 + (threadIdx.x >> 6);
  const int l   = threadIdx.x & 63;
  const float* src = (row < BATCH) ? (zi + (size_t)row * DIM)
                                   : (zj + (size_t)(row - BATCH) * DIM);
  const float4* s4 = (const float4*)src;
  float4 v0 = s4[l];
  float4 v1 = s4[l + 64];
  float ss = v0.x*v0.x + v0.y*v0.y + v0.z*v0.z + v0.w*v0.w
           + v1.x*v1.x + v1.y*v1.y + v1.z*v1.z + v1.w*v1.w;
  #pragma unroll
  for (int m = 1; m < 64; m <<= 1) ss += __shfl_xor(ss, m, 64);
  const float r = 64.0f / fmaxf(sqrtf(ss), 1e-12f);   // x64 prescale
  unsigned short p0 = (unsigned short)(q4(v0.x * r) | (q4(v0.y * r) << 4)
                     | (q4(v0.z * r) << 8) | (q4(v0.w * r) << 12));
  unsigned short p1 = (unsigned short)(q4(v1.x * r) | (q4(v1.y * r) << 4)
                     | (q4(v1.z * r) << 8) | (q4(v1.w * r) << 12));
  unsigned short* d = (unsigned short*)(zn + (size_t)row * 256);
  d[l]      = p0;    // k 4l..4l+3
  d[l + 64] = p1;    // k 256+4l..+3
}

// ---------------------------------------------------------------- main GEMM
// R15 MX-FP4 kernel with SINGLE-BUFFER FULL-K LDS (new in R16): at fp4 the
// whole 128x512 tile is 32KB/matrix, so both A and B fit in 64KB LDS at once.
// Structure: issue ALL 16 staging loads -> ONE __syncthreads -> 64 MFMAs with
// zero intermediate barriers (compiler pipelines all 32 ds_reads across the
// whole compute phase). Replaces the 2-buffer/4-barrier cadence whose drain
// latency dominated the (now tiny) per-iter compute. Not the failed R6/R7
// reordering — this REMOVES synchronization (4 barriers -> 1).
// LDS layout per matrix: 128 rows x 16 slots x 16B; slot s of row r holds
// k-chunk s ^ (r&15) (involution; inverse XOR on global source, dest linear).
// Read slot for (kk,quad) = (kk*4+quad) ^ (row&15), row&15 == lo; 16 lanes
// of a quad-group hit 16 distinct slots -> <=2-way bank alias = free (m136).
// acc = 4096*sim -> LS = 10/4096. Scales pinned 1.0 (E8M0 127), cbsz=blgp=4.
// Lessons pinned: MX-fp4 win (R15), MX-fp8 win (R14), fp8 win (R13).
// (256,3) hint regression (R12). rep-loop regression (R11). 256² regression
// (R10). Rule #20: no runtime array index into acc (R8/R9). BK=64-bf16
// regression (R7). depth-2 null (R6). NO fused loss tail (R3/R4). NO agent
// ACQ_REL (R1/R2). NO XCD swizzle. NO sched_barrier pinning (R1/m141).
__global__ __launch_bounds__(256) void simsum_kernel(const unsigned char* __restrict__ zn,
                                                     float* __restrict__ S,
                                                     float* __restrict__ P) {
  // triangle decode: u = bj*(bj+1)/2 + bi, bi <= bj < 64
  const int u = blockIdx.x;
  int bj = (int)((sqrtf(8.0f * (float)u + 1.0f) - 1.0f) * 0.5f);
  while ((bj + 1) * (bj + 2) / 2 <= u) ++bj;
  while (bj * (bj + 1) / 2 > u) --bj;
  const int bi = u - bj * (bj + 1) / 2;
  const bool diag = (bi == bj);
  const bool posb = (bj == bi + BATCH / 128);

  __shared__ __align__(16) unsigned char shA[32768];  // 128 rows x 256B
  __shared__ __align__(16) unsigned char shB[32768];
  __shared__ float redR[2][128];
  __shared__ float redC[2][128];

  const int t    = threadIdx.x;
  const int w    = t >> 6;
  const int l    = t & 63;
  const int quad = l >> 4;
  const int lo   = l & 15;
  const int wm   = w >> 1;
  const int wn   = w & 1;
  const int tileRow = bi * 128;
  const int tileCol = bj * 128;

  // staging: thread t stages chunks {t + 256m}, m=0..7, per matrix (2048
  // chunks = 128 rows x 16 slots). chunk p: row = p>>4, slot = p&15; content
  // k-chunk = slot ^ (row&15) = (t&15) ^ (t>>4) — CONSTANT per thread
  // (row advances by 16 per m). Dest = chunk*16, linear (HW adds lane*16).
  const int rr   = t >> 4;                       // 0..15
  const int koff = ((t & 15) ^ rr) * 16;
  #pragma unroll
  for (int m = 0; m < 8; ++m) {
    ASYNC16(zn + (size_t)(tileRow + rr + 16 * m) * 256 + koff,
            shA + w * 1024 + m * 4096);
    ASYNC16(zn + (size_t)(tileCol + rr + 16 * m) * 256 + koff,
            shB + w * 1024 + m * 4096);
  }

  floatx4 acc[4][4];
  #pragma unroll
  for (int i = 0; i < 4; ++i)
    #pragma unroll
    for (int j = 0; j < 4; ++j)
      acc[i][j] = (floatx4){0.f, 0.f, 0.f, 0.f};

  // fragment addressing: row = (wm|wn)*64 + i*16 + lo, row stride 256B;
  // byte in row = ((kk*4 + quad) ^ lo) * 16.
  const int aBase = (wm * 64 + lo) * 256;   // + i*4096
  const int bBase = (wn * 64 + lo) * 256;   // + j*4096

  __syncthreads();   // ONE barrier: drains all 16 staging loads (vmcnt(0))

  #pragma unroll
  for (int kk = 0; kk < 4; ++kk) {
    const int sw = ((kk * 4 + quad) ^ lo) * 16;
    union frag { int4 h[2]; intx8 v; };
    frag aF[4], bF[4];
    #pragma unroll
    for (int i = 0; i < 4; ++i) {
      aF[i].h[0] = *(const int4*)(shA + aBase + i * 4096 + sw);
      aF[i].h[1] = aF[i].h[0];   // fp4 uses low 4 regs; keep upper defined
    }
    #pragma unroll
    for (int j = 0; j < 4; ++j) {
      bF[j].h[0] = *(const int4*)(shB + bBase + j * 4096 + sw);
      bF[j].h[1] = bF[j].h[0];
    }
    #pragma unroll
    for (int i = 0; i < 4; ++i)
      #pragma unroll
      for (int j = 0; j < 4; ++j)
        // cbsz=4 (A=fp4), blgp=4 (B=fp4); scales = E8M0 127 = 1.0
        acc[i][j] = __builtin_amdgcn_mfma_scale_f32_16x16x128_f8f6f4(
            aF[i].v, bF[j].v, acc[i][j], 4, 4, 0, 127, 0, 127);
  }

  // ---- epilogue (identical to R15). C/D: col=lo, row=quad*4+r.
  const float LS = 10.0f / 4096.0f;
  float rs[4][4];
  float cs[4];
  #pragma unroll
  for (int i = 0; i < 4; ++i)
    #pragma unroll
    for (int r = 0; r < 4; ++r) rs[i][r] = 0.f;
  #pragma unroll
  for (int j = 0; j < 4; ++j) cs[j] = 0.f;

  #pragma unroll
  for (int i = 0; i < 4; ++i)
    #pragma unroll
    for (int j = 0; j < 4; ++j)
      #pragma unroll
      for (int r = 0; r < 4; ++r) {
        const float e = __expf(acc[i][j][r] * LS - 10.0f);
        rs[i][r] += e;
        cs[j] += e;
      }

  // block-local diagonal lanes: wm==wn, lo == quad*4 + r  (i.e. quad == lo>>2)
  if (wm == wn && quad == (lo >> 2)) {
    const int r = lo & 3;
    if (diag) {  // self-similarity: remove exp from both row and col sums
      #pragma unroll
      for (int i = 0; i < 4; ++i) {
        const float e = __expf(acc[i][i][r] * LS - 10.0f);
        rs[i][r] -= e;
        cs[i] -= e;
      }
    }
    if (posb) {  // positives: col == row + BATCH
      #pragma unroll
      for (int i = 0; i < 4; ++i) {
        const int row = tileRow + wm * 64 + i * 16 + lo;
        const float v = acc[i][i][r] * LS;
        P[row] = v;
        P[row + BATCH] = v;
      }
    }
  }

  // row sums: reduce across the 16 column-lanes (low 4 lane bits)
  #pragma unroll
  for (int m = 1; m < 16; m <<= 1) {
    #pragma unroll
    for (int i = 0; i < 4; ++i)
      #pragma unroll
      for (int r = 0; r < 4; ++r)
        rs[i][r] += __shfl_xor(rs[i][r], m, 64);
  }
  if (lo == 0) {
    #pragma unroll
    for (int i = 0; i < 4; ++i)
      #pragma unroll
      for (int r = 0; r < 4; ++r)
        redR[wn][wm * 64 + i * 16 + quad * 4 + r] = rs[i][r];
  }
  // col sums: reduce across the 4 quads (lane bits 4,5)
  #pragma unroll
  for (int m = 16; m < 64; m <<= 1) {
    #pragma unroll
    for (int j = 0; j < 4; ++j) cs[j] += __shfl_xor(cs[j], m, 64);
  }
  if (quad == 0) {
    #pragma unroll
    for (int j = 0; j < 4; ++j)
      redC[wm][wn * 64 + j * 16 + lo] = cs[j];
  }
  __syncthreads();
  if (t < 128) {
    atomicAdd(&S[tileRow + t], redR[0][t] + redR[1][t]);
  } else if (!diag) {
    const int c = t - 128;
    atomicAdd(&S[tileCol + c], redC[0][c] + redC[1][c]);
  }
  // waves retire here, fire-and-forget on the atomics (no drain — critical).
}

// ---------------------------------------------------------------- final loss
// 32 blocks x 256 threads, 1 element/thread; partial per block, one float
// atomicAdd into out[0] (zeroed by nrm).
__global__ __launch_bounds__(256) void loss_kernel(const float* __restrict__ S,
                                                   const float* __restrict__ P,
                                                   float* __restrict__ out) {
  const int i = blockIdx.x * 256 + threadIdx.x;
  float a = 10.0f + logf(S[i]) - P[i];
  #pragma unroll
  for (int m = 1; m < 64; m <<= 1) a += __shfl_xor(a, m, 64);
  __shared__ float sb[4];
  if ((threadIdx.x & 63) == 0) sb[threadIdx.x >> 6] = a;
  __syncthreads();
  if (threadIdx.x == 0)
    atomicAdd(out, (sb[0] + sb[1] + sb[2] + sb[3]) * (1.0f / (float)NTOT));
}

extern "C" void kernel_launch(void* const* d_in, const int* in_sizes, int n_in,
                              void* d_out, int out_size, void* d_ws, size_t ws_size,
                              hipStream_t stream) {
  const float* zi = (const float*)d_in[0];
  const float* zj = (const float*)d_in[1];
  unsigned char* zn = (unsigned char*)d_ws;                    // 8192*256 fp4 = 2 MB
  float*  S  = (float*)((char*)d_ws + (size_t)NTOT * DIM * 2); // (offset kept)
  float*  P  = S + NTOT;                                       // 32 KB
  float*  out = (float*)d_out;

  nrm_kernel<<<NTOT / 4, 256, 0, stream>>>(zi, zj, zn, S, out);
  simsum_kernel<<<NBLK, 256, 0, stream>>>(zn, S, P);
  loss_kernel<<<NTOT / 256, 256, 0, stream>>>(S, P, out);
}

// Round 17
// 90.596 us; speedup vs baseline: 1.0215x; 1.0215x over previous
//
#include <hip/hip_runtime.h>
#include <hip/hip_bf16.h>

#define BATCH 4096
#define NTOT  8192
#define DIM   512
#define NBLK  2080

typedef __attribute__((ext_vector_type(4))) float floatx4;
typedef __attribute__((ext_vector_type(8))) int   intx8;

#define ASYNC16(gp, lp)                                                        \
  __builtin_amdgcn_global_load_lds(                                            \
      (__attribute__((address_space(1))) void*)(gp),                           \
      (__attribute__((address_space(3))) void*)(lp), 16, 0, 0)

// e2m1 (OCP MXFP4) RNE quantizer for scaled value v; returns 4-bit code.
// Grid {0, 0.5, 1, 1.5, 2, 3, 4, 6}; code = index, sign in bit 3.
__device__ __forceinline__ unsigned q4(float v) {
  const float m = fabsf(v);
  int c;
  if      (m < 0.25f) c = 0;
  else if (m < 0.75f) c = 1;
  else if (m < 1.25f) c = 2;
  else if (m < 1.75f) c = 3;
  else if (m < 2.50f) c = 4;
  else if (m < 3.50f) c = 5;
  else if (m < 5.00f) c = 6;
  else                c = 7;
  return (unsigned)(c | (v < 0.0f ? 8 : 0));
}

// ---------------------------------------------------------------- normalize
// One wave per row: read 512 fp32, rsqrt(sum sq), write 512 fp4 e2m1 scaled
// by 64 (epilogue divides by 4096). Blocks 0..31 zero S; block 32 zeroes out.
__global__ __launch_bounds__(256) void nrm_kernel(const float* __restrict__ zi,
                                                  const float* __restrict__ zj,
                                                  unsigned char* __restrict__ zn,
                                                  float* __restrict__ S,
                                                  float* __restrict__ out) {
  if (blockIdx.x < 32) S[blockIdx.x * 256 + threadIdx.x] = 0.0f;
  if (blockIdx.x == 32 && threadIdx.x == 0) out[0] = 0.0f;
  const int row = blockIdx.x * 4 + (threadIdx.x >> 6);
  const int l   = threadIdx.x & 63;
  const float* src = (row < BATCH) ? (zi + (size_t)row * DIM)
                                   : (zj + (size_t)(row - BATCH) * DIM);
  const float4* s4 = (const float4*)src;
  float4 v0 = s4[l];
  float4 v1 = s4[l + 64];
  float ss = v0.x*v0.x + v0.y*v0.y + v0.z*v0.z + v0.w*v0.w
           + v1.x*v1.x + v1.y*v1.y + v1.z*v1.z + v1.w*v1.w;
  #pragma unroll
  for (int m = 1; m < 64; m <<= 1) ss += __shfl_xor(ss, m, 64);
  const float r = 64.0f / fmaxf(sqrtf(ss), 1e-12f);   // x64 prescale
  unsigned short p0 = (unsigned short)(q4(v0.x * r) | (q4(v0.y * r) << 4)
                     | (q4(v0.z * r) << 8) | (q4(v0.w * r) << 12));
  unsigned short p1 = (unsigned short)(q4(v1.x * r) | (q4(v1.y * r) << 4)
                     | (q4(v1.z * r) << 8) | (q4(v1.w * r) << 12));
  unsigned short* d = (unsigned short*)(zn + (size_t)row * 256);
  d[l]      = p0;    // k 4l..4l+3
  d[l + 64] = p1;    // k 256+4l..+3
}

// ---------------------------------------------------------------- main GEMM
// R15 CHAMPION, restored verbatim (89.5us e2e). 128x128 tile, 4 waves,
// 2-buffer LDS, one __syncthreads per K-iter, BK=128, MX-FP4 e2m1 via
// mfma_scale_f32_16x16x128_f8f6f4 (cbsz=blgp=4), scales pinned 1.0 (E8M0
// 127). acc = 4096*sim -> LS = 10/4096.
// R16 lesson (pinned): single-buffer full-K (1 barrier) REGRESSED +3us —
// the lone vmcnt(0) drain exposes the entire 64KB staging fill; the 2-buffer
// cadence keeps compute(k) overlapping staging(k+1). Exposed drain latency,
// not barrier count, is the cost. Keep 2-buffer.
// LDS layout per matrix/buffer: 128 rows x 4 slots x 16B; slot s of row r
// holds k-chunk s ^ (r&3) ^ ((r>>2)&3) (involution; inverse XOR applied on
// global source, dest linear). Fragment read slot = quad ^ (lo&3) ^
// ((lo>>2)&3): lanes {lo,lo+4,lo+8,lo+12} hit distinct 16B windows ->
// conflict-free b128.
// Full lesson ledger: MX-fp4 win (R15), MX-fp8 win (R14), fp8 win (R13).
// single-buffer full-K regression (R16). (256,3) hint regression (R12).
// rep-loop regression (R11). 256² regression (R10). Rule #20: no runtime
// array index into acc (R8/R9). BK=64-bf16 regression (R7). depth-2 null
// (R6). NO fused loss tail (R3/R4). NO agent ACQ_REL (R1/R2). NO XCD
// swizzle. NO sched_barrier pinning (R1/m141).
__global__ __launch_bounds__(256) void simsum_kernel(const unsigned char* __restrict__ zn,
                                                     float* __restrict__ S,
                                                     float* __restrict__ P) {
  // triangle decode: u = bj*(bj+1)/2 + bi, bi <= bj < 64
  const int u = blockIdx.x;
  int bj = (int)((sqrtf(8.0f * (float)u + 1.0f) - 1.0f) * 0.5f);
  while ((bj + 1) * (bj + 2) / 2 <= u) ++bj;
  while (bj * (bj + 1) / 2 > u) --bj;
  const int bi = u - bj * (bj + 1) / 2;
  const bool diag = (bi == bj);
  const bool posb = (bj == bi + BATCH / 128);

  __shared__ __align__(16) unsigned char shA[2 * 8192];  // 2 buf x 128 x 64B
  __shared__ __align__(16) unsigned char shB[2 * 8192];
  __shared__ float redR[2][128];
  __shared__ float redC[2][128];

  const int t    = threadIdx.x;
  const int w    = t >> 6;
  const int l    = t & 63;
  const int quad = l >> 4;
  const int lo   = l & 15;
  const int wm   = w >> 1;
  const int wn   = w & 1;
  const int tileRow = bi * 128;
  const int tileCol = bj * 128;

  // staging: thread t stages chunks {t, t+256} per matrix (512 chunks =
  // 128 rows x 4 slots x 16B per K-tile). chunk c: row r = c>>2, slot s=c&3;
  // content k-chunk = s ^ (r&3) ^ ((r>>2)&3). Second chunk: +64 rows, same
  // slot -> same XOR (64 = 0 mod 4 in both terms) -> koff constant/thread.
  const int rr   = t >> 2;                                    // 0..63
  const int koff = ((t & 3) ^ (rr & 3) ^ ((rr >> 2) & 3)) * 16;
  const unsigned char* gA0 = zn + (size_t)(tileRow + rr     ) * 256 + koff;
  const unsigned char* gA1 = zn + (size_t)(tileRow + rr + 64) * 256 + koff;
  const unsigned char* gB0 = zn + (size_t)(tileCol + rr     ) * 256 + koff;
  const unsigned char* gB1 = zn + (size_t)(tileCol + rr + 64) * 256 + koff;
  unsigned char* lA0 = shA + w * 1024;          // chunk t*16 (HW adds l*16)
  unsigned char* lA1 = shA + w * 1024 + 4096;   // chunk (t+256)*16
  unsigned char* lB0 = shB + w * 1024;
  unsigned char* lB1 = shB + w * 1024 + 4096;

  floatx4 acc[4][4];
  #pragma unroll
  for (int i = 0; i < 4; ++i)
    #pragma unroll
    for (int j = 0; j < 4; ++j)
      acc[i][j] = (floatx4){0.f, 0.f, 0.f, 0.f};

  // fragment reads: row = (wm|wn)*64 + i*16 + lo, row stride 64B;
  // quad needs k-chunk `quad` at slot quad ^ (lo&3) ^ ((lo>>2)&3).
  const int sw   = (quad ^ (lo & 3) ^ ((lo >> 2) & 3)) * 16;
  const int aRow = (wm * 64 + lo) * 64 + sw;   // + i*1024
  const int bRow = (wn * 64 + lo) * 64 + sw;   // + j*1024

  #define STAGE(bufo)                                                         \
    ASYNC16(gA0, lA0 + (bufo)); ASYNC16(gA1, lA1 + (bufo));                   \
    ASYNC16(gB0, lB0 + (bufo)); ASYNC16(gB1, lB1 + (bufo));                   \
    gA0 += 64; gA1 += 64; gB0 += 64; gB1 += 64;

  // prologue: stage K-tile 0 into buffer 0
  STAGE(0)

  #pragma unroll
  for (int it = 0; it < 4; ++it) {
    __syncthreads();  // drains loads for buffer `cur` (issued one iter ago)
    const int co = (it & 1) * 8192;
    const int no = co ^ 8192;
    if (it < 3) { STAGE(no) }
    union frag { int4 h[2]; intx8 v; };
    frag aF[4], bF[4];
    #pragma unroll
    for (int i = 0; i < 4; ++i) {
      aF[i].h[0] = *(const int4*)(shA + co + aRow + i * 1024);
      aF[i].h[1] = aF[i].h[0];   // fp4 uses low 4 regs; keep upper defined
    }
    #pragma unroll
    for (int j = 0; j < 4; ++j) {
      bF[j].h[0] = *(const int4*)(shB + co + bRow + j * 1024);
      bF[j].h[1] = bF[j].h[0];
    }
    #pragma unroll
    for (int i = 0; i < 4; ++i)
      #pragma unroll
      for (int j = 0; j < 4; ++j)
        // cbsz=4 (A=fp4), blgp=4 (B=fp4); scales = E8M0 127 = 1.0
        acc[i][j] = __builtin_amdgcn_mfma_scale_f32_16x16x128_f8f6f4(
            aF[i].v, bF[j].v, acc[i][j], 4, 4, 0, 127, 0, 127);
  }
  #undef STAGE

  // ---- epilogue. C/D: col=lo, row=quad*4+r. acc = 4096*sim.
  const float LS = 10.0f / 4096.0f;
  float rs[4][4];
  float cs[4];
  #pragma unroll
  for (int i = 0; i < 4; ++i)
    #pragma unroll
    for (int r = 0; r < 4; ++r) rs[i][r] = 0.f;
  #pragma unroll
  for (int j = 0; j < 4; ++j) cs[j] = 0.f;

  #pragma unroll
  for (int i = 0; i < 4; ++i)
    #pragma unroll
    for (int j = 0; j < 4; ++j)
      #pragma unroll
      for (int r = 0; r < 4; ++r) {
        const float e = __expf(acc[i][j][r] * LS - 10.0f);
        rs[i][r] += e;
        cs[j] += e;
      }

  // block-local diagonal lanes: wm==wn, lo == quad*4 + r  (i.e. quad == lo>>2)
  if (wm == wn && quad == (lo >> 2)) {
    const int r = lo & 3;
    if (diag) {  // self-similarity: remove exp from both row and col sums
      #pragma unroll
      for (int i = 0; i < 4; ++i) {
        const float e = __expf(acc[i][i][r] * LS - 10.0f);
        rs[i][r] -= e;
        cs[i] -= e;
      }
    }
    if (posb) {  // positives: col == row + BATCH
      #pragma unroll
      for (int i = 0; i < 4; ++i) {
        const int row = tileRow + wm * 64 + i * 16 + lo;
        const float v = acc[i][i][r] * LS;
        P[row] = v;
        P[row + BATCH] = v;
      }
    }
  }

  // row sums: reduce across the 16 column-lanes (low 4 lane bits)
  #pragma unroll
  for (int m = 1; m < 16; m <<= 1) {
    #pragma unroll
    for (int i = 0; i < 4; ++i)
      #pragma unroll
      for (int r = 0; r < 4; ++r)
        rs[i][r] += __shfl_xor(rs[i][r], m, 64);
  }
  if (lo == 0) {
    #pragma unroll
    for (int i = 0; i < 4; ++i)
      #pragma unroll
      for (int r = 0; r < 4; ++r)
        redR[wn][wm * 64 + i * 16 + quad * 4 + r] = rs[i][r];
  }
  // col sums: reduce across the 4 quads (lane bits 4,5)
  #pragma unroll
  for (int m = 16; m < 64; m <<= 1) {
    #pragma unroll
    for (int j = 0; j < 4; ++j) cs[j] += __shfl_xor(cs[j], m, 64);
  }
  if (quad == 0) {
    #pragma unroll
    for (int j = 0; j < 4; ++j)
      redC[wm][wn * 64 + j * 16 + lo] = cs[j];
  }
  __syncthreads();
  if (t < 128) {
    atomicAdd(&S[tileRow + t], redR[0][t] + redR[1][t]);
  } else if (!diag) {
    const int c = t - 128;
    atomicAdd(&S[tileCol + c], redC[0][c] + redC[1][c]);
  }
  // waves retire here, fire-and-forget on the atomics (no drain — critical).
}

// ---------------------------------------------------------------- final loss
// 32 blocks x 256 threads, 1 element/thread; partial per block, one float
// atomicAdd into out[0] (zeroed by nrm).
__global__ __launch_bounds__(256) void loss_kernel(const float* __restrict__ S,
                                                   const float* __restrict__ P,
                                                   float* __restrict__ out) {
  const int i = blockIdx.x * 256 + threadIdx.x;
  float a = 10.0f + logf(S[i]) - P[i];
  #pragma unroll
  for (int m = 1; m < 64; m <<= 1) a += __shfl_xor(a, m, 64);
  __shared__ float sb[4];
  if ((threadIdx.x & 63) == 0) sb[threadIdx.x >> 6] = a;
  __syncthreads();
  if (threadIdx.x == 0)
    atomicAdd(out, (sb[0] + sb[1] + sb[2] + sb[3]) * (1.0f / (float)NTOT));
}

extern "C" void kernel_launch(void* const* d_in, const int* in_sizes, int n_in,
                              void* d_out, int out_size, void* d_ws, size_t ws_size,
                              hipStream_t stream) {
  const float* zi = (const float*)d_in[0];
  const float* zj = (const float*)d_in[1];
  unsigned char* zn = (unsigned char*)d_ws;                    // 8192*256 fp4 = 2 MB
  float*  S  = (float*)((char*)d_ws + (size_t)NTOT * DIM * 2); // (offset kept)
  float*  P  = S + NTOT;                                       // 32 KB
  float*  out = (float*)d_out;

  nrm_kernel<<<NTOT / 4, 256, 0, stream>>>(zi, zj, zn, S, out);
  simsum_kernel<<<NBLK, 256, 0, stream>>>(zn, S, P);
  loss_kernel<<<NTOT / 256, 256, 0, stream>>>(S, P, out);
}